// Round 2
// baseline (20531.467 us; speedup 1.0000x reference)
//
#include <hip/hip_runtime.h>
#include <hip/hip_bf16.h>

// GPT forward, fp32 (round 1: 128x128 GEMM tile + flash attention).
// L=8, B=2, T=2048, E=1024, H=16, V=32000, DH=64.

#define LAYERS 8
#define BB 2
#define TT 2048
#define EE 1024
#define HH 16
#define VV 32000
#define DHD 64
#define MROWS (BB * TT)   // 4096

// ---------------- embed: x = tok_emb[idx] + pos_emb[t] ----------------
__global__ __launch_bounds__(256) void embed_kernel(
    const int* __restrict__ idx, const float* __restrict__ tok,
    const float* __restrict__ pos, float* __restrict__ x) {
  int row = blockIdx.x;              // 0..MROWS-1
  int t = row & (TT - 1);
  int tokid = idx[row];
  int c = threadIdx.x * 4;           // 256 threads * 4 = 1024 = E
  float4 a = *(const float4*)(tok + (size_t)tokid * EE + c);
  float4 p = *(const float4*)(pos + (size_t)t * EE + c);
  a.x += p.x; a.y += p.y; a.z += p.z; a.w += p.w;
  *(float4*)(x + (size_t)row * EE + c) = a;
}

// ---------------- GEMM: C[M,N] = A[M,K] @ W[K,N] (+bias)(+relu) ----------------
// BM=BN=128, BK=16, 256 threads, 8x8 micro-tile per thread (4 quadrants of 4x4).
// LDS reads: 4x b128 per kk, all addresses <=2-way bank-aliased (free on CDNA4).
template <int BIAS, int RELU>
__global__ __launch_bounds__(256) void gemm_kernel(
    const float* __restrict__ A, const float* __restrict__ W,
    const float* __restrict__ bias, float* __restrict__ C,
    int M, int N, int K) {
  __shared__ float As[16][132];   // As[k][m] (transposed stage)
  __shared__ float Ws[16][132];   // Ws[k][n]
  const int tid = threadIdx.x;
  const int m0 = blockIdx.y * 128, n0 = blockIdx.x * 128;
  const int ty = tid >> 4, tx = tid & 15;
  const int ar = tid >> 1, akq = (tid & 1) * 8;   // A: row 0..127, k-half
  const int wr = tid >> 4, wc = (tid & 15) * 8;   // W: krow 0..15, col-half
  const float* Ap = A + (size_t)(m0 + ar) * K + akq;
  const float* Wp = W + (size_t)wr * N + n0 + wc;
  float acc[8][8] = {};
  for (int k0 = 0; k0 < K; k0 += 16) {
    float4 a0 = *(const float4*)(Ap + k0);
    float4 a1 = *(const float4*)(Ap + k0 + 4);
    float4 w0 = *(const float4*)(Wp + (size_t)k0 * N);
    float4 w1 = *(const float4*)(Wp + (size_t)k0 * N + 4);
    __syncthreads();   // previous iter's readers done before overwrite
    As[akq + 0][ar] = a0.x;
    As[akq + 1][ar] = a0.y;
    As[akq + 2][ar] = a0.z;
    As[akq + 3][ar] = a0.w;
    As[akq + 4][ar] = a1.x;
    As[akq + 5][ar] = a1.y;
    As[akq + 6][ar] = a1.z;
    As[akq + 7][ar] = a1.w;
    *(float4*)&Ws[wr][wc] = w0;
    *(float4*)&Ws[wr][wc + 4] = w1;
    __syncthreads();
#pragma unroll
    for (int kk = 0; kk < 16; ++kk) {
      float4 alo = *(const float4*)&As[kk][ty * 4];
      float4 ahi = *(const float4*)&As[kk][64 + ty * 4];
      float4 blo = *(const float4*)&Ws[kk][tx * 4];
      float4 bhi = *(const float4*)&Ws[kk][64 + tx * 4];
      float av[8] = {alo.x, alo.y, alo.z, alo.w, ahi.x, ahi.y, ahi.z, ahi.w};
      float bv[8] = {blo.x, blo.y, blo.z, blo.w, bhi.x, bhi.y, bhi.z, bhi.w};
#pragma unroll
      for (int i = 0; i < 8; ++i)
#pragma unroll
        for (int j = 0; j < 8; ++j) acc[i][j] += av[i] * bv[j];
    }
  }
  float4 blo4 = make_float4(0.f, 0.f, 0.f, 0.f), bhi4 = blo4;
  if (BIAS) {
    blo4 = *(const float4*)(bias + n0 + tx * 4);
    bhi4 = *(const float4*)(bias + n0 + 64 + tx * 4);
  }
#pragma unroll
  for (int i = 0; i < 8; ++i) {
    int row = m0 + ty * 4 + (i & 3) + (i >> 2) * 64;
    float* Cp = C + (size_t)row * N + n0;
    float4 r0, r1;
    r0.x = acc[i][0] + blo4.x; r0.y = acc[i][1] + blo4.y;
    r0.z = acc[i][2] + blo4.z; r0.w = acc[i][3] + blo4.w;
    r1.x = acc[i][4] + bhi4.x; r1.y = acc[i][5] + bhi4.y;
    r1.z = acc[i][6] + bhi4.z; r1.w = acc[i][7] + bhi4.w;
    if (RELU) {
      r0.x = fmaxf(r0.x, 0.f); r0.y = fmaxf(r0.y, 0.f);
      r0.z = fmaxf(r0.z, 0.f); r0.w = fmaxf(r0.w, 0.f);
      r1.x = fmaxf(r1.x, 0.f); r1.y = fmaxf(r1.y, 0.f);
      r1.z = fmaxf(r1.z, 0.f); r1.w = fmaxf(r1.w, 0.f);
    }
    *(float4*)(Cp + tx * 4) = r0;
    *(float4*)(Cp + 64 + tx * 4) = r1;
  }
}

// ---------------- flash attention (single pass, causal) ----------------
// block = 16 q-rows x (b,h). 256 threads: thread (r16,g16) owns score cols
// 4*g16..+3 in the score phase and output dims 4*g16..+3 in the PV phase.
// LDS 44KB -> 3 blocks/CU. All hot-loop LDS accesses are b128, <=2-way.
__global__ __launch_bounds__(256) void attn_kernel(
    const float* __restrict__ q, const float* __restrict__ k,
    const float* __restrict__ v, float* __restrict__ o) {
  __shared__ float qs[16][68];
  __shared__ float kT[64][68];   // kT[d][krow]
  __shared__ float vs[64][68];   // vs[krow][d]
  __shared__ float ps[16][68];
  int bh = blockIdx.y;
  int b = bh >> 4, h = bh & 15;
  int q0 = blockIdx.x * 16;
  int tid = threadIdx.x;
  int r16 = tid >> 4, g16 = tid & 15;
  int c = g16 * 4;
  {
    const float* qp = q + (size_t)(b * TT + q0 + r16) * EE + h * DHD + c;
    float4 q4 = *(const float4*)qp;
    const float s = 0.125f;  // DH^-0.5
    qs[r16][c + 0] = q4.x * s;
    qs[r16][c + 1] = q4.y * s;
    qs[r16][c + 2] = q4.z * s;
    qs[r16][c + 3] = q4.w * s;
  }
  int qrow = q0 + r16;
  int kend = q0 + 16;
  float m = -1e30f, ssum = 0.f;
  float o0 = 0.f, o1 = 0.f, o2 = 0.f, o3 = 0.f;
  const int k_row = tid & 15, k_d = (tid >> 4) * 4;   // K stage mapping
  const int v_row = tid >> 4, v_d = (tid & 15) * 4;   // V stage mapping
  for (int kb = 0; kb < kend; kb += 64) {
    __syncthreads();   // prev PV reads done (and qs published, 1st iter)
#pragma unroll
    for (int it = 0; it < 4; ++it) {
      int kr = k_row + it * 16;
      float4 k4 = *(const float4*)(k + (size_t)(b * TT + kb + kr) * EE + h * DHD + k_d);
      kT[k_d + 0][kr] = k4.x;
      kT[k_d + 1][kr] = k4.y;
      kT[k_d + 2][kr] = k4.z;
      kT[k_d + 3][kr] = k4.w;
      int vr = v_row + it * 16;
      float4 v4 = *(const float4*)(v + (size_t)(b * TT + kb + vr) * EE + h * DHD + v_d);
      *(float4*)&vs[vr][v_d] = v4;
    }
    __syncthreads();
    float s0 = 0.f, s1 = 0.f, s2 = 0.f, s3 = 0.f;
#pragma unroll 8
    for (int d = 0; d < 64; ++d) {
      float qv = qs[r16][d];
      float4 kd = *(const float4*)&kT[d][c];
      s0 += qv * kd.x; s1 += qv * kd.y; s2 += qv * kd.z; s3 += qv * kd.w;
    }
    int col = kb + c;
    if (col + 0 > qrow) s0 = -1e30f;
    if (col + 1 > qrow) s1 = -1e30f;
    if (col + 2 > qrow) s2 = -1e30f;
    if (col + 3 > qrow) s3 = -1e30f;
    float mt = fmaxf(fmaxf(s0, s1), fmaxf(s2, s3));
#pragma unroll
    for (int off = 8; off; off >>= 1) mt = fmaxf(mt, __shfl_xor(mt, off, 16));
    float mnew = fmaxf(m, mt);
    float scale = __expf(m - mnew);
    float p0 = __expf(s0 - mnew), p1 = __expf(s1 - mnew);
    float p2 = __expf(s2 - mnew), p3 = __expf(s3 - mnew);
    float psum = p0 + p1 + p2 + p3;
#pragma unroll
    for (int off = 8; off; off >>= 1) psum += __shfl_xor(psum, off, 16);
    ssum = ssum * scale + psum;
    m = mnew;
    o0 *= scale; o1 *= scale; o2 *= scale; o3 *= scale;
    *(float4*)&ps[r16][c] = make_float4(p0, p1, p2, p3);
    __syncthreads();   // ps visible to whole row-group
#pragma unroll 8
    for (int kk = 0; kk < 64; ++kk) {
      float pv = ps[r16][kk];
      float4 v4 = *(const float4*)&vs[kk][c];
      o0 += pv * v4.x; o1 += pv * v4.y; o2 += pv * v4.z; o3 += pv * v4.w;
    }
  }
  float inv = 1.0f / ssum;
  float4 r;
  r.x = o0 * inv; r.y = o1 * inv; r.z = o2 * inv; r.w = o3 * inv;
  *(float4*)(o + (size_t)(b * TT + q0 + r16) * EE + h * DHD + c) = r;
}

// ---------------- LayerNorm (optionally fused residual add) ----------------
__device__ __forceinline__ float block_reduce(float v, float* tmp) {
#pragma unroll
  for (int off = 32; off > 0; off >>= 1) v += __shfl_down(v, off);
  int wid = threadIdx.x >> 6, lane = threadIdx.x & 63;
  __syncthreads();
  if (lane == 0) tmp[wid] = v;
  __syncthreads();
  return tmp[0] + tmp[1] + tmp[2] + tmp[3];
}

template <int ADD>
__global__ __launch_bounds__(256) void ln_kernel(
    const float* __restrict__ X, const float* __restrict__ Y,
    const float* __restrict__ sg, const float* __restrict__ bg,
    float* __restrict__ out) {
  __shared__ float tmp[4];
  int row = blockIdx.x;
  int c = threadIdx.x * 4;
  float4 xv = *(const float4*)(X + (size_t)row * EE + c);
  if (ADD) {
    float4 yv = *(const float4*)(Y + (size_t)row * EE + c);
    xv.x += yv.x; xv.y += yv.y; xv.z += yv.z; xv.w += yv.w;
  }
  float s = xv.x + xv.y + xv.z + xv.w;
  float mean = block_reduce(s, tmp) * (1.0f / EE);
  float dx = xv.x - mean, dy = xv.y - mean, dz = xv.z - mean, dw = xv.w - mean;
  float sq = dx * dx + dy * dy + dz * dz + dw * dw;
  float var = block_reduce(sq, tmp) * (1.0f / EE);
  float inv = rsqrtf(var + 1e-5f);
  float4 s4 = *(const float4*)(sg + c);
  float4 b4 = *(const float4*)(bg + c);
  float4 r;
  r.x = dx * inv * s4.x + b4.x;
  r.y = dy * inv * s4.y + b4.y;
  r.z = dz * inv * s4.z + b4.z;
  r.w = dw * inv * s4.w + b4.w;
  *(float4*)(out + (size_t)row * EE + c) = r;
}

// ---------------- host ----------------
extern "C" void kernel_launch(void* const* d_in, const int* in_sizes, int n_in,
                              void* d_out, int out_size, void* d_ws, size_t ws_size,
                              hipStream_t stream) {
  const int*   index   = (const int*)  d_in[0];
  const float* tok_emb = (const float*)d_in[1];
  const float* pos_emb = (const float*)d_in[2];
  const float* wq      = (const float*)d_in[3];
  const float* wk      = (const float*)d_in[4];
  const float* wv      = (const float*)d_in[5];
  const float* wproj   = (const float*)d_in[6];
  const float* bproj   = (const float*)d_in[7];
  const float* w1      = (const float*)d_in[8];
  const float* b1      = (const float*)d_in[9];
  const float* w2      = (const float*)d_in[10];
  const float* b2      = (const float*)d_in[11];
  const float* ln1_s   = (const float*)d_in[12];
  const float* ln1_b   = (const float*)d_in[13];
  const float* ln2_s   = (const float*)d_in[14];
  const float* ln2_b   = (const float*)d_in[15];
  const float* lnf_s   = (const float*)d_in[16];
  const float* lnf_b   = (const float*)d_in[17];
  const float* w_lm    = (const float*)d_in[18];
  const float* b_lm    = (const float*)d_in[19];
  float* out = (float*)d_out;

  float* ws = (float*)d_ws;
  const size_t NX = (size_t)MROWS * EE;   // 4M floats
  float* x  = ws;
  float* y  = ws + NX;
  float* qb = ws + 2 * NX;
  float* kb = ws + 3 * NX;
  float* vb = ws + 4 * NX;
  float* ob = ws + 5 * NX;
  float* h1 = ws + 6 * NX;                // 16M floats (MLP hidden)

  dim3 blk(256);
  embed_kernel<<<MROWS, blk, 0, stream>>>(index, tok_emb, pos_emb, x);

  for (int l = 0; l < LAYERS; ++l) {
    const float* wql = wq + (size_t)l * EE * EE;
    const float* wkl = wk + (size_t)l * EE * EE;
    const float* wvl = wv + (size_t)l * EE * EE;
    const float* wpl = wproj + (size_t)l * EE * EE;
    const float* bpl = bproj + (size_t)l * EE;
    const float* w1l = w1 + (size_t)l * EE * 4 * EE;
    const float* b1l = b1 + (size_t)l * 4 * EE;
    const float* w2l = w2 + (size_t)l * 4 * EE * EE;
    const float* b2l = b2 + (size_t)l * EE;

    gemm_kernel<0, 0><<<dim3(EE / 128, MROWS / 128), blk, 0, stream>>>(
        x, wql, nullptr, qb, MROWS, EE, EE);
    gemm_kernel<0, 0><<<dim3(EE / 128, MROWS / 128), blk, 0, stream>>>(
        x, wkl, nullptr, kb, MROWS, EE, EE);
    gemm_kernel<0, 0><<<dim3(EE / 128, MROWS / 128), blk, 0, stream>>>(
        x, wvl, nullptr, vb, MROWS, EE, EE);

    attn_kernel<<<dim3(TT / 16, BB * HH), blk, 0, stream>>>(qb, kb, vb, ob);

    gemm_kernel<1, 0><<<dim3(EE / 128, MROWS / 128), blk, 0, stream>>>(
        ob, wpl, bpl, y, MROWS, EE, EE);
    ln_kernel<1><<<MROWS, blk, 0, stream>>>(x, y, ln1_s + (size_t)l * EE,
                                            ln1_b + (size_t)l * EE, x);

    gemm_kernel<1, 1><<<dim3(4 * EE / 128, MROWS / 128), blk, 0, stream>>>(
        x, w1l, b1l, h1, MROWS, 4 * EE, EE);
    gemm_kernel<1, 0><<<dim3(EE / 128, MROWS / 128), blk, 0, stream>>>(
        h1, w2l, b2l, y, MROWS, EE, 4 * EE);
    ln_kernel<1><<<MROWS, blk, 0, stream>>>(x, y, ln2_s + (size_t)l * EE,
                                            ln2_b + (size_t)l * EE, x);
  }

  ln_kernel<0><<<MROWS, blk, 0, stream>>>(x, nullptr, lnf_s, lnf_b, y);
  gemm_kernel<1, 0><<<dim3(VV / 128, MROWS / 128), blk, 0, stream>>>(
      y, w_lm, b_lm, out, MROWS, VV, EE);
}